// Round 1
// baseline (5676.297 us; speedup 1.0000x reference)
//
#include <hip/hip_runtime.h>
#include <math.h>

typedef unsigned short u16;
typedef unsigned int   u32;
typedef float fx4 __attribute__((ext_vector_type(4)));
typedef short sh8 __attribute__((ext_vector_type(8)));
typedef u16   us4 __attribute__((ext_vector_type(4)));

typedef __attribute__((address_space(1))) u32 gas_u32;
typedef __attribute__((address_space(3))) u32 las_u32;

__device__ __forceinline__ u16 f2bf(float f){
  union { float f; u32 u; } v; v.f = f;
  return (u16)((v.u + 0x7FFFu + ((v.u >> 16) & 1u)) >> 16);
}
__device__ __forceinline__ float bf2f(u16 h){
  union { u32 u; float f; } v; v.u = ((u32)h) << 16; return v.f;
}
__device__ __forceinline__ fx4 mfma16(sh8 a, sh8 b, fx4 c){
  return __builtin_amdgcn_mfma_f32_16x16x32_bf16(a, b, c, 0, 0, 0);
}
__device__ __forceinline__ void async16(const void* g, void* l){
  __builtin_amdgcn_global_load_lds((const gas_u32*)g, (las_u32*)l, 16, 0, 0);
}

// ---------------- generic transpose + fp32->bf16 convert: src[K][N] -> dst[N][K]
__global__ __launch_bounds__(256) void transpose_cvt(const float* __restrict__ src,
                                                     u16* __restrict__ dst, int K, int N)
{
  __shared__ float tile[32][33];
  const int tx = threadIdx.x, ty = threadIdx.y;
  const int nb = blockIdx.x * 32, kb = blockIdx.y * 32;
  if (nb >= N || kb >= K) return;
  #pragma unroll
  for (int i = ty; i < 32; i += 8){
    int kk = kb + i, nn = nb + tx;
    tile[i][tx] = (kk < K && nn < N) ? src[(size_t)kk * N + nn] : 0.f;
  }
  __syncthreads();
  #pragma unroll
  for (int i = ty; i < 32; i += 8){
    int nn = nb + i, kk = kb + tx;
    if (nn < N && kk < K) dst[(size_t)nn * K + kk] = f2bf(tile[tx][i]);
  }
}

// ---------------- per-layer fused transposes (qw,kw,vw,ow: 768x768; fcw: 768x3072; pw: 3072x768)
__global__ __launch_bounds__(256) void transpose_layer_k(
    const float* __restrict__ qw, const float* __restrict__ kw,
    const float* __restrict__ vw, const float* __restrict__ ow,
    const float* __restrict__ fcw, const float* __restrict__ pw,
    u16* __restrict__ qwT, u16* __restrict__ kwT, u16* __restrict__ vwT,
    u16* __restrict__ owT, u16* __restrict__ fcwT, u16* __restrict__ pwT, int l)
{
  const int z = blockIdx.z;
  const float* src; u16* dst; int K, N;
  switch (z){
    case 0: src = qw + (size_t)l*589824;  dst = qwT;  K = 768;  N = 768;  break;
    case 1: src = kw + (size_t)l*589824;  dst = kwT;  K = 768;  N = 768;  break;
    case 2: src = vw + (size_t)l*589824;  dst = vwT;  K = 768;  N = 768;  break;
    case 3: src = ow + (size_t)l*589824;  dst = owT;  K = 768;  N = 768;  break;
    case 4: src = fcw + (size_t)l*2359296; dst = fcwT; K = 768;  N = 3072; break;
    default: src = pw + (size_t)l*2359296; dst = pwT;  K = 3072; N = 768;  break;
  }
  int ntile, ktile;
  if (z == 5){ ktile = blockIdx.x; ntile = blockIdx.y; }
  else       { ntile = blockIdx.x; ktile = blockIdx.y; }
  if (ntile * 32 >= N || ktile * 32 >= K) return;
  __shared__ float tile[32][33];
  const int tx = threadIdx.x, ty = threadIdx.y;
  const int nb = ntile * 32, kb = ktile * 32;
  #pragma unroll
  for (int i = ty; i < 32; i += 8)
    tile[i][tx] = src[(size_t)(kb + i) * N + nb + tx];
  __syncthreads();
  #pragma unroll
  for (int i = ty; i < 32; i += 8)
    dst[(size_t)(nb + i) * K + kb + tx] = f2bf(tile[tx][i]);
}

// ---------------- patch gather: faithful replication of the scrambled flatten
__global__ __launch_bounds__(256) void gather_k(const float* __restrict__ x, u16* __restrict__ t)
{
  int idx = blockIdx.x * 256 + threadIdx.x;      // one thread = 4 consecutive outputs
  int o = idx * 4;                                // < 3538944
  int p1  = o / 221184;                           // 221184 = (B*C*GH*GW)*P
  int rem = o - p1 * 221184;
  int bcgg = rem >> 4, p2 = rem & 15;
  int gw = bcgg % 24; int t1 = bcgg / 24;
  int gh = t1 % 24;   int t2 = t1 / 24;
  int c  = t2 % 3;    int bb = t2 / 3;
  size_t src = ((size_t)((bb * 3 + c) * 384 + gh * 16 + p1)) * 384 + gw * 16 + p2;
  fx4 v = *(const fx4*)&x[src];
  us4 r;
  #pragma unroll
  for (int j = 0; j < 4; j++) r[j] = f2bf(v[j]);
  *(us4*)&t[o] = r;
}

// ---------------- CLS row init: h[b*577][:] = cls + pos[0]
__global__ void cls_k(float* __restrict__ H, const float* __restrict__ cls,
                      const float* __restrict__ pos)
{
  int b = blockIdx.x;
  for (int j = threadIdx.x; j < 768; j += 256)
    H[(size_t)(b * 577) * 768 + j] = cls[j] + pos[j];
}

// ---------------- LayerNorm (fp32 in, bf16 out), one wave per row
__global__ __launch_bounds__(256) void ln_k(const float* __restrict__ H,
    const float* __restrict__ g, const float* __restrict__ b,
    u16* __restrict__ Y, int rows, int row_stride)
{
  int row  = blockIdx.x * 4 + (threadIdx.x >> 6);
  int lane = threadIdx.x & 63;
  if (row >= rows) return;
  const float* hp = H + (size_t)row * row_stride;
  fx4 v0 = *(const fx4*)&hp[lane * 4];
  fx4 v1 = *(const fx4*)&hp[256 + lane * 4];
  fx4 v2 = *(const fx4*)&hp[512 + lane * 4];
  float s = 0.f, sq = 0.f;
  #pragma unroll
  for (int j = 0; j < 4; j++){ s += v0[j] + v1[j] + v2[j];
    sq += v0[j]*v0[j] + v1[j]*v1[j] + v2[j]*v2[j]; }
  #pragma unroll
  for (int o = 32; o; o >>= 1){ s += __shfl_xor(s, o, 64); sq += __shfl_xor(sq, o, 64); }
  float mean = s * (1.f / 768.f);
  float var  = sq * (1.f / 768.f) - mean * mean;
  float rr   = rsqrtf(var + 1e-5f);
  u16* yp = Y + (size_t)row * 768;
  us4 o0, o1, o2;
  #pragma unroll
  for (int j = 0; j < 4; j++){
    o0[j] = f2bf((v0[j] - mean) * rr * g[lane*4 + j]       + b[lane*4 + j]);
    o1[j] = f2bf((v1[j] - mean) * rr * g[256 + lane*4 + j] + b[256 + lane*4 + j]);
    o2[j] = f2bf((v2[j] - mean) * rr * g[512 + lane*4 + j] + b[512 + lane*4 + j]);
  }
  *(us4*)&yp[lane * 4]       = o0;
  *(us4*)&yp[256 + lane * 4] = o1;
  *(us4*)&yp[512 + lane * 4] = o2;
}

// ---------------- main GEMM: C[M,N] = A[M,K](bf16) * BT[N,K]^T(bf16), templated epilogue
enum { EPI_BF16 = 0, EPI_GELU = 1, EPI_RESID = 2, EPI_VT = 3, EPI_EMB = 4 };

template<int EPI>
__global__ __launch_bounds__(256)
void gemm_k(const u16* __restrict__ A, const u16* __restrict__ BT,
            const float* __restrict__ bias, u16* __restrict__ Cb,
            float* __restrict__ Cf, const float* __restrict__ aux,
            int M, int N, int K)
{
  __shared__ u16 lA[4096];
  __shared__ u16 lB[4096];
  const int tid = threadIdx.x, wid = tid >> 6, lane = tid & 63;
  const int lr = lane & 15, lg = lane >> 4;
  const int row0 = blockIdx.y * 128, col0 = blockIdx.x * 128;
  const int wr = (wid >> 1) * 64, wc = (wid & 1) * 64;

  fx4 acc[4][4];
  #pragma unroll
  for (int i = 0; i < 4; i++)
    #pragma unroll
    for (int j = 0; j < 4; j++) acc[i][j] = (fx4){0.f, 0.f, 0.f, 0.f};

  int ar0 = row0 + lane;      if (ar0 > M - 1) ar0 = M - 1;
  int ar1 = row0 + 64 + lane; if (ar1 > M - 1) ar1 = M - 1;
  const u16* gA0 = A  + (size_t)ar0 * K + wid * 8;
  const u16* gA1 = A  + (size_t)ar1 * K + wid * 8;
  const u16* gB0 = BT + (size_t)(col0 + lane) * K + wid * 8;
  const u16* gB1 = BT + (size_t)(col0 + 64 + lane) * K + wid * 8;
  u16* lA0 = &lA[(wid * 2 + 0) * 512];
  u16* lA1 = &lA[(wid * 2 + 1) * 512];
  u16* lB0 = &lB[(wid * 2 + 0) * 512];
  u16* lB1 = &lB[(wid * 2 + 1) * 512];

  const int aoff = (lg * 128 + wr + lr) * 8;
  const int boff = (lg * 128 + wc + lr) * 8;

  for (int k0 = 0; k0 < K; k0 += 32){
    __syncthreads();
    async16(gA0 + k0, lA0);
    async16(gA1 + k0, lA1);
    async16(gB0 + k0, lB0);
    async16(gB1 + k0, lB1);
    __syncthreads();
    sh8 af[4], bfr[4];
    #pragma unroll
    for (int mr = 0; mr < 4; mr++) af[mr]  = *(const sh8*)&lA[aoff + mr * 128];
    #pragma unroll
    for (int nr = 0; nr < 4; nr++) bfr[nr] = *(const sh8*)&lB[boff + nr * 128];
    #pragma unroll
    for (int mr = 0; mr < 4; mr++)
      #pragma unroll
      for (int nr = 0; nr < 4; nr++)
        acc[mr][nr] = mfma16(af[mr], bfr[nr], acc[mr][nr]);
  }

  #pragma unroll
  for (int mr = 0; mr < 4; mr++){
    #pragma unroll
    for (int r = 0; r < 4; r++){
      const int grow = row0 + wr + mr * 16 + lg * 4 + r;
      if (grow >= M) continue;
      #pragma unroll
      for (int nr = 0; nr < 4; nr++){
        const int gcol = col0 + wc + nr * 16 + lr;
        float v = acc[mr][nr][r] + bias[gcol];
        if constexpr (EPI == EPI_BF16){
          Cb[(size_t)grow * N + gcol] = f2bf(v);
        } else if constexpr (EPI == EPI_GELU){
          float gl = 0.5f * v * (1.0f + erff(v * 0.70710678118654752f));
          Cb[(size_t)grow * N + gcol] = f2bf(gl);
        } else if constexpr (EPI == EPI_RESID){
          float* pp = Cf + (size_t)grow * N + gcol;
          *pp += v;
        } else if constexpr (EPI == EPI_VT){
          int bb = grow / 577, n = grow - bb * 577;
          int hh = gcol >> 6, hd = gcol & 63;
          Cb[((size_t)((bb * 12 + hh) * 64 + hd)) * 608 + n] = f2bf(v);
        } else { // EPI_EMB: remap row b*576+np -> h row b*577+1+np, add pos_emb
          int bb = grow / 576, np = grow - bb * 576;
          Cf[((size_t)(bb * 577 + 1 + np)) * 768 + gcol] = v + aux[(size_t)(1 + np) * 768 + gcol];
        }
      }
    }
  }
}

// ---------------- fused attention: one wg = (b, h, 64 q-rows); wave = 16 q-rows
__global__ __launch_bounds__(256) void attn_k(const u16* __restrict__ Q,
    const u16* __restrict__ Km, const u16* __restrict__ VT, u16* __restrict__ O)
{
  __shared__ u16 Plds[4][16 * 40];   // per-wave P chunk [16 rows][32 cols], stride 40
  const int tid = threadIdx.x, wid = tid >> 6, lane = tid & 63;
  const int lr = lane & 15, lg = lane >> 4;
  const int bh = blockIdx.y, b = bh / 12, hh = bh - b * 12;
  const int qr0 = blockIdx.x * 64 + wid * 16;

  int qrow = qr0 + lr; int qrc = qrow > 576 ? 576 : qrow;
  const u16* qp = Q + ((size_t)(b * 577 + qrc)) * 768 + hh * 64 + lg * 8;
  sh8 qf0 = *(const sh8*)qp;
  sh8 qf1 = *(const sh8*)(qp + 32);

  fx4 s[38];
  #pragma unroll
  for (int mt = 0; mt < 38; mt++){
    int mrow = mt * 16 + lr; int mrc = mrow > 576 ? 576 : mrow;
    const u16* kp = Km + ((size_t)(b * 577 + mrc)) * 768 + hh * 64 + lg * 8;
    sh8 k0 = *(const sh8*)kp;
    sh8 k1 = *(const sh8*)(kp + 32);
    fx4 a = (fx4){0.f, 0.f, 0.f, 0.f};
    a = mfma16(qf0, k0, a);
    a = mfma16(qf1, k1, a);
    s[mt] = a;
  }

  float mx[4] = {-3e38f, -3e38f, -3e38f, -3e38f};
  #pragma unroll
  for (int mt = 0; mt < 38; mt++){
    int m = mt * 16 + lr;
    #pragma unroll
    for (int r = 0; r < 4; r++){
      float v = (m <= 576) ? s[mt][r] * 0.125f : -1e30f;  // overwrite-mask pad keys
      s[mt][r] = v;
      mx[r] = fmaxf(mx[r], v);
    }
  }
  #pragma unroll
  for (int o = 1; o < 16; o <<= 1)
    #pragma unroll
    for (int r = 0; r < 4; r++) mx[r] = fmaxf(mx[r], __shfl_xor(mx[r], o, 64));
  float sm[4] = {0.f, 0.f, 0.f, 0.f};
  #pragma unroll
  for (int mt = 0; mt < 38; mt++)
    #pragma unroll
    for (int r = 0; r < 4; r++){ float pv = __expf(s[mt][r] - mx[r]); s[mt][r] = pv; sm[r] += pv; }
  #pragma unroll
  for (int o = 1; o < 16; o <<= 1)
    #pragma unroll
    for (int r = 0; r < 4; r++) sm[r] += __shfl_xor(sm[r], o, 64);
  float rin[4];
  #pragma unroll
  for (int r = 0; r < 4; r++) rin[r] = 1.0f / sm[r];

  u16* Pw = &Plds[wid][0];
  fx4 oacc[4];
  #pragma unroll
  for (int nt = 0; nt < 4; nt++) oacc[nt] = (fx4){0.f, 0.f, 0.f, 0.f};

  for (int ch = 0; ch < 19; ch++){
    #pragma unroll
    for (int c = 0; c < 2; c++){
      int mt = ch * 2 + c;
      #pragma unroll
      for (int r = 0; r < 4; r++)
        Pw[(lg * 4 + r) * 40 + c * 16 + lr] = f2bf(s[mt][r] * rin[r]);
    }
    sh8 pa = *(const sh8*)&Pw[lr * 40 + lg * 8];   // same-wave DS ordering: in-order
    #pragma unroll
    for (int nt = 0; nt < 4; nt++){
      const u16* vp = VT + ((size_t)((b * 12 + hh) * 64 + nt * 16 + lr)) * 608 + ch * 32 + lg * 8;
      sh8 vf = *(const sh8*)vp;
      oacc[nt] = mfma16(pa, vf, oacc[nt]);
    }
  }

  #pragma unroll
  for (int nt = 0; nt < 4; nt++)
    #pragma unroll
    for (int r = 0; r < 4; r++){
      int orow = qr0 + lg * 4 + r;
      if (orow <= 576)
        O[((size_t)(b * 577 + orow)) * 768 + hh * 64 + nt * 16 + lr] = f2bf(oacc[nt][r]);
    }
}

// ---------------- classification head: 8x1000, bf16 dots
__global__ __launch_bounds__(256) void head_k(const u16* __restrict__ clsn,
    const u16* __restrict__ hwT, const float* __restrict__ hb, float* __restrict__ out)
{
  int gid = blockIdx.x * 256 + threadIdx.x;
  if (gid >= 8000) return;
  int b = gid / 1000, o = gid - b * 1000;
  const u16* a = clsn + b * 768;
  const u16* w = hwT + (size_t)o * 768;
  float acc = 0.f;
  for (int i = 0; i < 768; i += 8){
    sh8 av = *(const sh8*)&a[i];
    sh8 wv = *(const sh8*)&w[i];
    #pragma unroll
    for (int j = 0; j < 8; j++) acc += bf2f((u16)av[j]) * bf2f((u16)wv[j]);
  }
  out[gid] = acc + hb[o];
}

extern "C" void kernel_launch(void* const* d_in, const int* in_sizes, int n_in,
                              void* d_out, int out_size, void* d_ws, size_t ws_size,
                              hipStream_t stream)
{
  const float* x       = (const float*)d_in[0];
  const float* proj_w  = (const float*)d_in[1];
  const float* proj_b  = (const float*)d_in[2];
  const float* cls_emb = (const float*)d_in[3];
  const float* pos_emb = (const float*)d_in[4];
  const float* ln1_g   = (const float*)d_in[5];
  const float* ln1_b   = (const float*)d_in[6];
  const float* qw      = (const float*)d_in[7];
  const float* qb      = (const float*)d_in[8];
  const float* kw      = (const float*)d_in[9];
  const float* kb      = (const float*)d_in[10];
  const float* vw      = (const float*)d_in[11];
  const float* vb      = (const float*)d_in[12];
  const float* ow      = (const float*)d_in[13];
  const float* ob      = (const float*)d_in[14];
  const float* ln2_g   = (const float*)d_in[15];
  const float* ln2_b   = (const float*)d_in[16];
  const float* fcw     = (const float*)d_in[17];
  const float* fcb     = (const float*)d_in[18];
  const float* pw      = (const float*)d_in[19];
  const float* pb      = (const float*)d_in[20];
  const float* lnf_g   = (const float*)d_in[21];
  const float* lnf_b   = (const float*)d_in[22];
  const float* head_w  = (const float*)d_in[23];
  const float* head_b  = (const float*)d_in[24];
  float* out = (float*)d_out;

  char* p = (char*)d_ws;
  auto take = [&](size_t bytes) -> char* {
    char* r = p; p += (bytes + 255) & ~(size_t)255; return r;
  };
  u16*  projwT = (u16*)take((size_t)589824 * 2);
  u16*  headwT = (u16*)take((size_t)768000 * 2);
  u16*  t      = (u16*)take((size_t)3538944 * 2);
  float* h     = (float*)take((size_t)3545088 * 4);
  u16*  y      = (u16*)take((size_t)3545088 * 2);
  u16*  q      = (u16*)take((size_t)3545088 * 2);
  u16*  kbuf   = (u16*)take((size_t)3545088 * 2);
  u16*  vT     = (u16*)take((size_t)3735552 * 2);
  u16*  ao     = (u16*)take((size_t)3545088 * 2);
  u16*  mid    = (u16*)take((size_t)14180352 * 2);
  u16*  qwT    = (u16*)take((size_t)589824 * 2);
  u16*  kwT    = (u16*)take((size_t)589824 * 2);
  u16*  vwT    = (u16*)take((size_t)589824 * 2);
  u16*  owT    = (u16*)take((size_t)589824 * 2);
  u16*  fcwT   = (u16*)take((size_t)2359296 * 2);
  u16*  pwT    = (u16*)take((size_t)2359296 * 2);
  u16*  clsn   = (u16*)take((size_t)8 * 768 * 2);
  (void)ws_size; (void)in_sizes; (void)n_in; (void)out_size;

  dim3 tb(32, 8);
  transpose_cvt<<<dim3(24, 24), tb, 0, stream>>>(proj_w, projwT, 768, 768);
  transpose_cvt<<<dim3(32, 24), tb, 0, stream>>>(head_w, headwT, 768, 1000);
  gather_k<<<3456, 256, 0, stream>>>(x, t);
  gemm_k<EPI_EMB><<<dim3(6, 36), 256, 0, stream>>>(t, projwT, proj_b, nullptr, h, pos_emb, 4608, 768, 768);
  cls_k<<<8, 256, 0, stream>>>(h, cls_emb, pos_emb);

  for (int l = 0; l < 12; l++){
    transpose_layer_k<<<dim3(96, 24, 6), tb, 0, stream>>>(qw, kw, vw, ow, fcw, pw,
                                                          qwT, kwT, vwT, owT, fcwT, pwT, l);
    ln_k<<<1154, 256, 0, stream>>>(h, ln1_g + l * 768, ln1_b + l * 768, y, 4616, 768);
    gemm_k<EPI_BF16><<<dim3(6, 37), 256, 0, stream>>>(y, qwT, qb + l * 768, q, nullptr, nullptr, 4616, 768, 768);
    gemm_k<EPI_BF16><<<dim3(6, 37), 256, 0, stream>>>(y, kwT, kb + l * 768, kbuf, nullptr, nullptr, 4616, 768, 768);
    gemm_k<EPI_VT><<<dim3(6, 37), 256, 0, stream>>>(y, vwT, vb + l * 768, vT, nullptr, nullptr, 4616, 768, 768);
    attn_k<<<dim3(10, 96), 256, 0, stream>>>(q, kbuf, vT, ao);
    gemm_k<EPI_RESID><<<dim3(6, 37), 256, 0, stream>>>(ao, owT, ob + l * 768, nullptr, h, nullptr, 4616, 768, 768);
    ln_k<<<1154, 256, 0, stream>>>(h, ln2_g + l * 768, ln2_b + l * 768, y, 4616, 768);
    gemm_k<EPI_GELU><<<dim3(24, 37), 256, 0, stream>>>(y, fcwT, fcb + l * 3072, mid, nullptr, nullptr, 4616, 3072, 768);
    gemm_k<EPI_RESID><<<dim3(6, 37), 256, 0, stream>>>(mid, pwT, pb + l * 768, nullptr, h, nullptr, 4616, 768, 3072);
  }
  ln_k<<<2, 256, 0, stream>>>(h, lnf_g, lnf_b, clsn, 8, 577 * 768);
  head_k<<<32, 256, 0, stream>>>(clsn, headwT, head_b, out);
}